// Round 12
// baseline (188.692 us; speedup 1.0000x reference)
//
#include <hip/hip_runtime.h>
#include <hip/hip_bf16.h>
#include <cstdint>

#define B_ 4
#define S_ 2048
#define D_ 1024
#define H_ 16
#define DK_ 64

typedef _Float16 h8 __attribute__((ext_vector_type(8)));
typedef _Float16 h4 __attribute__((ext_vector_type(4)));
typedef float f32x4 __attribute__((ext_vector_type(4)));
typedef float f32x16 __attribute__((ext_vector_type(16)));
typedef unsigned int u32x4 __attribute__((ext_vector_type(4)));

// async global->LDS, 16B per lane. LDS dest = wave-uniform base + lane*16.
__device__ __forceinline__ void gload16(const void* src, void* lds) {
  __builtin_amdgcn_global_load_lds((const __attribute__((address_space(1))) void*)src,
                                   (__attribute__((address_space(3))) void*)lds, 16, 0, 0);
}

// ---------------- fused convert: x->f16, weights->f16 (QKV concat), bias ----
__global__ __launch_bounds__(256) void conv_all(
    const float* __restrict__ x,
    const float* __restrict__ Wq, const float* __restrict__ Wk,
    const float* __restrict__ Wv, const float* __restrict__ Wo,
    const float* __restrict__ bq, const float* __restrict__ bk,
    const float* __restrict__ bv,
    _Float16* __restrict__ xb, _Float16* __restrict__ wqkv,
    _Float16* __restrict__ wo, float* __restrict__ bqkv) {
  const int bid = blockIdx.x, tid = threadIdx.x;
  if (bid < 4096) {  // x: 8.39M f32, 8 per thread
    int base = (bid * 256 + tid) * 8;
    h8 o;
#pragma unroll
    for (int j = 0; j < 8; ++j) o[j] = (_Float16)x[base + j];
    *(h8*)(xb + base) = o;
  } else {  // weights: 4 x 1M f32, 8 per thread
    int i = (bid - 4096) * 256 + tid;
    int seg = i >> 17, r = i & 131071;
    const float* src = seg == 0 ? Wq : seg == 1 ? Wk : seg == 2 ? Wv : Wo;
    int base = r * 8;
    h8 o;
#pragma unroll
    for (int j = 0; j < 8; ++j) o[j] = (_Float16)src[base + j];
    if (seg < 3)
      *(h8*)(wqkv + (size_t)seg * 1048576 + base) = o;
    else
      *(h8*)(wo + base) = o;
    if (i < 768) {  // bias concat: 3 x 1024 f32
      int bsel = i >> 8, k = (i & 255) * 4;
      const float* bs = bsel == 0 ? bq : bsel == 1 ? bk : bv;
      float4 v = *(const float4*)(bs + k);
      *(float4*)(bqkv + bsel * 1024 + k) = v;
    }
  }
}

// ---------------- NT GEMM: (MI*32)x128 block, 4 waves, wave tile (MI*16)x64 -
// r8's PROVEN coalesced staging (8 lanes per 128B line, XOR-swizzled source,
// linear LDS dest) + XOR-swizzled row-major LDS reads (0 conflicts).
// MODE 0 (MI=8): N=3072 QKV fused; Q,K -> [2][B,H,S,DK] f16; V -> Vt.
// MODE 1 (MI=4): N=1024, f32 out [M][1024], grid (8,64) for 2 blocks/CU.
template <int MODE, int MI>
__global__ __launch_bounds__(256, 2) void gemm_nt(const _Float16* __restrict__ A,
                                                  const _Float16* __restrict__ Bw,
                                                  const float* __restrict__ bias,
                                                  void* __restrict__ Cout,
                                                  _Float16* __restrict__ Vt) {
  constexpr int ABYTES = MI * 4096;       // (MI*32) rows x 64 k x 2B
  __shared__ char lds[ABYTES + 16384];    // A row-major+swz, B at +ABYTES

  const int tid = threadIdx.x;
  const int w = tid >> 6, lane = tid & 63, g = lane >> 4, c = lane & 15;
  const int wm = w >> 1, wn = w & 1;
  const int bn = blockIdx.x;  // N/128
  const int bm = blockIdx.y;  // M/(MI*32)

  f32x4 acc[MI][4] = {};

  // staging invariants: pass j covers lin = j*4096 + tid*16;
  // row = j*32 + (tid>>3); col = (tid&7)*16, inverse-swizzled.
  const int srow = tid >> 3;
  const int scolsw = ((tid & 7) * 16) ^ ((srow & 7) << 4);
  const char* Ab = (const char*)A + (size_t)bm * (MI * 32) * 2048;
  const char* Bb = (const char*)Bw + (size_t)bn * 128 * 2048;
  const char* Asrc[MI];
  const char* Bsrc[4];
#pragma unroll
  for (int j = 0; j < MI; ++j)
    Asrc[j] = Ab + (size_t)(j * 32 + srow) * 2048 + scolsw;
#pragma unroll
  for (int j = 0; j < 4; ++j)
    Bsrc[j] = Bb + (size_t)(j * 32 + srow) * 2048 + scolsw;
  char* dstA = lds + w * 1024;
  char* dstB = lds + ABYTES + w * 1024;

  for (int k0 = 0; k0 < 2048; k0 += 128) {  // K byte offset, 16 iters
    __syncthreads();  // previous compute done reading LDS
#pragma unroll
    for (int j = 0; j < MI; ++j) gload16(Asrc[j] + k0, dstA + j * 4096);
#pragma unroll
    for (int j = 0; j < 4; ++j) gload16(Bsrc[j] + k0, dstB + j * 4096);
    __syncthreads();  // vmcnt drained at barrier -> tile ready

#pragma unroll
    for (int kk = 0; kk < 2; ++kk) {
      h8 b[4];
#pragma unroll
      for (int ni = 0; ni < 4; ++ni) {
        int row = wn * 64 + ni * 16 + c;
        int off = row * 128 + kk * 64 + g * 16;
        b[ni] = *(const h8*)(lds + ABYTES + (off ^ ((row & 7) << 4)));
      }
      h8 a[MI];
#pragma unroll
      for (int mi = 0; mi < MI; ++mi) {
        int row = wm * (MI * 16) + mi * 16 + c;
        int off = row * 128 + kk * 64 + g * 16;
        a[mi] = *(const h8*)(lds + (off ^ ((row & 7) << 4)));
      }
      __builtin_amdgcn_s_setprio(1);
#pragma unroll
      for (int mi = 0; mi < MI; ++mi)
#pragma unroll
        for (int ni = 0; ni < 4; ++ni)
          acc[mi][ni] = __builtin_amdgcn_mfma_f32_16x16x32_f16(a[mi], b[ni], acc[mi][ni], 0, 0, 0);
      __builtin_amdgcn_s_setprio(0);
    }
  }

  if (MODE == 0 && bn >= 16) {
    // V segment -> Vt [bh][dk][s]: 4 consecutive s rows -> one h4 store
#pragma unroll
    for (int mi = 0; mi < MI; ++mi)
#pragma unroll
      for (int ni = 0; ni < 4; ++ni) {
        int m0 = bm * (MI * 32) + wm * (MI * 16) + mi * 16 + g * 4;
        int n = bn * 128 + wn * 64 + ni * 16 + c;
        float bb = bias[n];
        h4 v4;
#pragma unroll
        for (int r = 0; r < 4; ++r) v4[r] = (_Float16)(acc[mi][ni][r] + bb);
        int bI = m0 >> 11, sI = m0 & 2047;
        int dk = n & 63, hh = (n >> 6) & 15;
        *(h4*)(Vt + (((size_t)(bI * 16 + hh) * 64 + dk) * 2048 + sI)) = v4;
      }
  } else {
#pragma unroll
    for (int mi = 0; mi < MI; ++mi)
#pragma unroll
      for (int ni = 0; ni < 4; ++ni)
#pragma unroll
        for (int r = 0; r < 4; ++r) {
          int m = bm * (MI * 32) + wm * (MI * 16) + mi * 16 + g * 4 + r;
          int n = bn * 128 + wn * 64 + ni * 16 + c;
          float v = acc[mi][ni][r] + bias[n];
          if (MODE == 0) {
            int which = n >> 10, nn = n & 1023;
            int bI = m >> 11, sI = m & 2047, hI = nn >> 6, dkI = nn & 63;
            ((_Float16*)Cout)[(size_t)which * 8388608 +
                              (((size_t)bI * H_ + hI) * S_ + sI) * DK_ + dkI] = (_Float16)v;
          } else {
            ((float*)Cout)[(size_t)m * D_ + n] = v;
          }
        }
  }
}

// ---------------- causal flash attention ------------------------------------
// r11 math verbatim; grid restructured to 512 blocks (ONE 256q supertile per
// block) -> 2 blocks/CU = 16 waves/CU. Co-resident blocks (bid, bid+256) have
// sup summing to 7 (uniform 36 tiles/CU, LPT: longest first) and share the
// same bh (K/V L2 reads shared). 8-wave 32x32 MFMA, in-reg P, blk-major K/V
// LDS (0 conflicts), 3-slot ring, counted vmcnt(2), raw barriers.
__global__ __launch_bounds__(512) void attn_fwd(const _Float16* __restrict__ Q,
                                                const _Float16* __restrict__ K,
                                                const _Float16* __restrict__ Vt,
                                                _Float16* __restrict__ vals) {
  __shared__ char lds[3 * 16384];  // 48KB ring

  const int tid = threadIdx.x;
  const int w = tid >> 6;            // wave 0..7
  const int lane = tid & 63;
  const int l31 = lane & 31, hi = lane >> 5;
  const int bid = blockIdx.x;        // 512 = 8 quads x 64 bh
  const int quad = bid >> 6;         // 0..7
  const int sup = (quad < 4) ? 7 - quad : quad - 4;  // pairs (bid,bid+256) sum to 7
  const int bh = bid & 63;           // bh-inner -> per-XCD L2 residency
  const int bI = bh >> 4, hI = bh & 15;

  const char* Qb = (const char*)(Q + (size_t)bh * S_ * DK_);
  const char* Kb = (const char*)(K + (size_t)bh * S_ * DK_);
  const char* Vtb = (const char*)(Vt + (size_t)bh * DK_ * S_);

  // staging: blk-major transpose via per-lane source (LDS dest linear).
  auto stage = [&](int sloti, int kv0) {
    char* buf = lds + sloti * 16384;
    gload16(Kb + (size_t)kv0 * 128 + (size_t)lane * 128 + w * 16, buf + w * 1024);
    gload16(Vtb + (size_t)lane * 4096 + (size_t)kv0 * 2 + w * 16, buf + 8192 + w * 1024);
  };

  // fragment read offsets: contiguous 16B x 32 lanes (conflict-free)
  int rdo[4];
#pragma unroll
  for (int ks = 0; ks < 4; ++ks) rdo[ks] = (ks * 2 + hi) * 1024 + l31 * 16;

  const _Float16 qsc = (_Float16)(0.125f * 1.44269504f);  // scale * log2(e)

  const int qw = sup * 8 + w;                  // this wave's 32q tile
  const int nt = 4 * sup + 4;                  // block-uniform tiles

  h8 qf[4];
#pragma unroll
  for (int ks = 0; ks < 4; ++ks) {
    h8 v = *(const h8*)(Qb + (size_t)(qw * 32 + l31) * 128 + ks * 32 + hi * 16);
#pragma unroll
    for (int j = 0; j < 8; ++j) v[j] *= qsc;
    qf[ks] = v;
  }

  f32x16 o[2] = {};                 // dk 0..31, 32..63
  float m_ = -1e30f, l_ = 0.f;

  stage(0, 0);
  stage(1, 64);
  asm volatile("s_waitcnt vmcnt(2)" ::: "memory");  // tile 0 landed
  __builtin_amdgcn_s_barrier();
  asm volatile("" ::: "memory");

  for (int t = 0; t < nt; ++t) {
    const char* ldsb = lds + (t % 3) * 16384;
    if (t + 2 < nt) stage((t + 2) % 3, (t + 2) * 64);

    const int rel = qw - 2 * t;
    if (rel >= 0) {
      const bool have1 = (rel >= 1);

      // S^T = K Q^T : C col = q = l31, row kv = (r&3)+8*(r>>2)+4*hi (+32)
      f32x16 s0 = {}, s1 = {};
#pragma unroll
      for (int ks = 0; ks < 4; ++ks) {
        h8 k0 = *(const h8*)(ldsb + rdo[ks]);
        __builtin_amdgcn_s_setprio(1);
        s0 = __builtin_amdgcn_mfma_f32_32x32x16_f16(k0, qf[ks], s0, 0, 0, 0);
        __builtin_amdgcn_s_setprio(0);
        if (have1) {
          h8 k1 = *(const h8*)(ldsb + rdo[ks] + 512);
          __builtin_amdgcn_s_setprio(1);
          s1 = __builtin_amdgcn_mfma_f32_32x32x16_f16(k1, qf[ks], s1, 0, 0, 0);
          __builtin_amdgcn_s_setprio(0);
        }
      }

      if (rel == 0) {
#pragma unroll
        for (int r = 0; r < 16; ++r) {
          int rowidx = (r & 3) + 8 * (r >> 2) + 4 * hi;
          if (rowidx > l31) s0[r] = -1e30f;
        }
      } else if (rel == 1) {
#pragma unroll
        for (int r = 0; r < 16; ++r) {
          int rowidx = (r & 3) + 8 * (r >> 2) + 4 * hi;
          if (rowidx > l31) s1[r] = -1e30f;
        }
      }

      // per-lane max tree
      float t8[8];
#pragma unroll
      for (int j = 0; j < 8; ++j) t8[j] = fmaxf(s0[2 * j], s0[2 * j + 1]);
      if (have1)
#pragma unroll
        for (int j = 0; j < 8; ++j) t8[j] = fmaxf(t8[j], fmaxf(s1[2 * j], s1[2 * j + 1]));
      float t4a = fmaxf(t8[0], t8[1]), t4b = fmaxf(t8[2], t8[3]);
      float t4c = fmaxf(t8[4], t8[5]), t4d = fmaxf(t8[6], t8[7]);
      float pmax = fmaxf(fmaxf(t4a, t4b), fmaxf(t4c, t4d));

      // defer-max: no cross-lane reduce in common path
      if (!__all(pmax <= m_ + 8.f)) {
        float rm = fmaxf(pmax, __shfl_xor(pmax, 32));
        float mn = fmaxf(m_, rm);
        float al = __builtin_amdgcn_exp2f(m_ - mn);
        m_ = mn;
        l_ *= al;
#pragma unroll
        for (int r = 0; r < 16; ++r) {
          float av = __shfl(al, (r & 3) + 8 * (r >> 2) + 4 * hi);
          o[0][r] *= av;
          o[1][r] *= av;
        }
      }

      // exp2 + pack to u32 kv-pair words, partial sums
      unsigned int u0[8], u1[8];
      float rsa = 0.f, rsb = 0.f;
#pragma unroll
      for (int j = 0; j < 8; ++j) {
        float e0 = __builtin_amdgcn_exp2f(s0[2 * j] - m_);
        float e1 = __builtin_amdgcn_exp2f(s0[2 * j + 1] - m_);
        rsa += e0 + e1;
        u0[j] = __builtin_bit_cast(unsigned int, __builtin_amdgcn_cvt_pkrtz(e0, e1));
      }
      if (have1) {
#pragma unroll
        for (int j = 0; j < 8; ++j) {
          float e0 = __builtin_amdgcn_exp2f(s1[2 * j] - m_);
          float e1 = __builtin_amdgcn_exp2f(s1[2 * j + 1] - m_);
          rsb += e0 + e1;
          u1[j] = __builtin_bit_cast(unsigned int, __builtin_amdgcn_cvt_pkrtz(e0, e1));
        }
      }
      l_ += rsa + rsb;

      // rebuild PV A-operand in registers: half-swap via shfl_xor(.,32)
      h8 pa0[2], pa1[2];
#pragma unroll
      for (int b = 0; b < 2; ++b) {
        unsigned int ua = u0[4 * b], ub = u0[4 * b + 1];
        unsigned int uc = u0[4 * b + 2], ud = u0[4 * b + 3];
        unsigned int va = hi ? ua : uc, vb = hi ? ub : ud;
        unsigned int xa = __shfl_xor(va, 32), xb = __shfl_xor(vb, 32);
        u32x4 q = {hi ? xa : ua, hi ? xb : ub, hi ? uc : xa, hi ? ud : xb};
        pa0[b] = __builtin_bit_cast(h8, q);
      }
      if (have1) {
#pragma unroll
        for (int b = 0; b < 2; ++b) {
          unsigned int ua = u1[4 * b], ub = u1[4 * b + 1];
          unsigned int uc = u1[4 * b + 2], ud = u1[4 * b + 3];
          unsigned int va = hi ? ua : uc, vb = hi ? ub : ud;
          unsigned int xa = __shfl_xor(va, 32), xb = __shfl_xor(vb, 32);
          u32x4 q = {hi ? xa : ua, hi ? xb : ub, hi ? uc : xa, hi ? ud : xb};
          pa1[b] = __builtin_bit_cast(h8, q);
        }
      }

      // O += P V : B col = dk = l31 (+x*32 -> +512B), k = kv 16-slices
#pragma unroll
      for (int x = 0; x < 2; ++x) {
#pragma unroll
        for (int kvs = 0; kvs < 4; ++kvs) {
          int ni = kvs >> 1, b = kvs & 1;
          if (!have1 && ni == 1) continue;
          h8 vf = *(const h8*)(ldsb + 8192 + rdo[kvs] + x * 512);
          h8 pa = ni ? pa1[b] : pa0[b];
          __builtin_amdgcn_s_setprio(1);
          o[x] = __builtin_amdgcn_mfma_f32_32x32x16_f16(pa, vf, o[x], 0, 0, 0);
          __builtin_amdgcn_s_setprio(0);
        }
      }
    }

    if (t + 2 < nt)
      asm volatile("s_waitcnt vmcnt(2)" ::: "memory");
    else
      asm volatile("s_waitcnt vmcnt(0)" ::: "memory");
    __builtin_amdgcn_s_barrier();
    asm volatile("" ::: "memory");
  }

  // epilogue
  float lt = l_ + __shfl_xor(l_, 32);
  float linv = 1.0f / lt;
#pragma unroll
  for (int r = 0; r < 16; ++r) {
    int qidx = (r & 3) + 8 * (r >> 2) + 4 * hi;
    float inv = __shfl(linv, qidx);
    int qrow = qw * 32 + qidx;
    size_t rowoff = ((size_t)bI * S_ + qrow) * D_ + hI * 64 + l31;
    vals[rowoff] = (_Float16)(o[0][r] * inv);
    vals[rowoff + 32] = (_Float16)(o[1][r] * inv);
  }
}

extern "C" void kernel_launch(void* const* d_in, const int* in_sizes, int n_in,
                              void* d_out, int out_size, void* d_ws, size_t ws_size,
                              hipStream_t stream) {
  const float* x  = (const float*)d_in[0];
  // d_in[1] = mask (fixed causal tril) — hardcoded in attn_fwd
  const float* Wq = (const float*)d_in[2];
  const float* bq = (const float*)d_in[3];
  const float* Wk = (const float*)d_in[4];
  const float* bk = (const float*)d_in[5];
  const float* Wv = (const float*)d_in[6];
  const float* bv = (const float*)d_in[7];
  const float* Wo = (const float*)d_in[8];
  const float* bo = (const float*)d_in[9];
  float* out = (float*)d_out;

  char* ws = (char*)d_ws;
  size_t off = 0;
  auto alloc = [&](size_t bytes) {
    char* p = ws + off;
    off += (bytes + 255) & ~(size_t)255;
    return p;
  };
  _Float16* xb   = (_Float16*)alloc((size_t)B_ * S_ * D_ * 2);           // 16MB
  _Float16* wqkv = (_Float16*)alloc((size_t)3 * D_ * D_ * 2);            // 6MB
  _Float16* wob  = (_Float16*)alloc((size_t)D_ * D_ * 2);                // 2MB
  float*    bqkv = (float*)alloc((size_t)3 * D_ * 4);                    // 12KB
  _Float16* qkvw = (_Float16*)alloc((size_t)2 * B_ * H_ * S_ * DK_ * 2); // 32MB (Q,K)
  _Float16* Vtw  = (_Float16*)alloc((size_t)B_ * H_ * S_ * DK_ * 2);     // 16MB
  _Float16* valw = (_Float16*)alloc((size_t)B_ * S_ * D_ * 2);           // 16MB

  conv_all<<<6144, 256, 0, stream>>>(x, Wq, Wk, Wv, Wo, bq, bk, bv, xb, wqkv, wob, bqkv);

  // fused QKV projection; V written transposed straight to Vtw
  gemm_nt<0, 8><<<dim3(24, 32), 256, 0, stream>>>(xb, wqkv, bqkv, qkvw, Vtw);

  attn_fwd<<<512, 512, 0, stream>>>(qkvw, qkvw + (size_t)8388608, Vtw, valw);

  gemm_nt<1, 4><<<dim3(8, 64), 256, 0, stream>>>(valw, wob, bo, out, nullptr);
}

// Round 13
// 181.333 us; speedup vs baseline: 1.0406x; 1.0406x over previous
//
#include <hip/hip_runtime.h>
#include <hip/hip_bf16.h>
#include <cstdint>

#define B_ 4
#define S_ 2048
#define D_ 1024
#define H_ 16
#define DK_ 64

typedef _Float16 h8 __attribute__((ext_vector_type(8)));
typedef _Float16 h4 __attribute__((ext_vector_type(4)));
typedef float f32x4 __attribute__((ext_vector_type(4)));
typedef float f32x16 __attribute__((ext_vector_type(16)));
typedef unsigned int u32x4 __attribute__((ext_vector_type(4)));

// async global->LDS, 16B per lane. LDS dest = wave-uniform base + lane*16.
__device__ __forceinline__ void gload16(const void* src, void* lds) {
  __builtin_amdgcn_global_load_lds((const __attribute__((address_space(1))) void*)src,
                                   (__attribute__((address_space(3))) void*)lds, 16, 0, 0);
}

// ---------------- fused convert: x->f16, weights->f16 (QKV concat), bias ----
__global__ __launch_bounds__(256) void conv_all(
    const float* __restrict__ x,
    const float* __restrict__ Wq, const float* __restrict__ Wk,
    const float* __restrict__ Wv, const float* __restrict__ Wo,
    const float* __restrict__ bq, const float* __restrict__ bk,
    const float* __restrict__ bv,
    _Float16* __restrict__ xb, _Float16* __restrict__ wqkv,
    _Float16* __restrict__ wo, float* __restrict__ bqkv) {
  const int bid = blockIdx.x, tid = threadIdx.x;
  if (bid < 4096) {  // x: 8.39M f32, 8 per thread
    int base = (bid * 256 + tid) * 8;
    h8 o;
#pragma unroll
    for (int j = 0; j < 8; ++j) o[j] = (_Float16)x[base + j];
    *(h8*)(xb + base) = o;
  } else {  // weights: 4 x 1M f32, 8 per thread
    int i = (bid - 4096) * 256 + tid;
    int seg = i >> 17, r = i & 131071;
    const float* src = seg == 0 ? Wq : seg == 1 ? Wk : seg == 2 ? Wv : Wo;
    int base = r * 8;
    h8 o;
#pragma unroll
    for (int j = 0; j < 8; ++j) o[j] = (_Float16)src[base + j];
    if (seg < 3)
      *(h8*)(wqkv + (size_t)seg * 1048576 + base) = o;
    else
      *(h8*)(wo + base) = o;
    if (i < 768) {  // bias concat: 3 x 1024 f32
      int bsel = i >> 8, k = (i & 255) * 4;
      const float* bs = bsel == 0 ? bq : bsel == 1 ? bk : bv;
      float4 v = *(const float4*)(bs + k);
      *(float4*)(bqkv + bsel * 1024 + k) = v;
    }
  }
}

// ---------------- pipelined NT GEMM: 256x128 tile, 8 waves, BK=64 ----------
// T3-minimal + T4: double-buffered LDS (2 x 48KB), per iter:
//   stage(t+1) -> vmcnt(6) [own stage(t) landed] -> barrier [all stage(t)
//   landed] -> ds_read+MFMA slot t -> barrier [slot t released].
// Slot safety: stage(t+1) writes slot (t+1)&1, which was released by the
// closing barrier of iter t-1. Loads never drain mid-loop (vmcnt(6) keeps
// stage(t+1) in flight). Staging/swizzle = r11's proven coalesced pattern
// (8 lanes per 128B line, XOR-swizzled source col, swizzled reads, 0 confl).
// 8 waves as 4(wm) x 2(wn); wave tile 64x64, acc 4x4.
// MODE 0: N=3072 QKV fused; Q,K -> [2][B,H,S,DK] f16; V -> Vt [B,H,DK,S].
// MODE 1: N=1024, f32 out [M][1024].
template <int MODE>
__global__ __launch_bounds__(512, 1) void gemm_pipe(const _Float16* __restrict__ A,
                                                    const _Float16* __restrict__ Bw,
                                                    const float* __restrict__ bias,
                                                    void* __restrict__ Cout,
                                                    _Float16* __restrict__ Vt) {
  __shared__ char lds[2 * 49152];  // 96KB: 2 slots x (A 32KB + B 16KB)

  const int tid = threadIdx.x;
  const int w = tid >> 6, lane = tid & 63, g = lane >> 4, c = lane & 15;
  const int wm = w >> 1, wn = w & 1;
  const int bn = blockIdx.x;  // N/128
  const int bm = blockIdx.y;  // M/256 = 32

  f32x4 acc[4][4] = {};

  // staging: pass j covers lin = j*8192 + tid*16; row = j*64 + (tid>>3);
  // col = (tid&7)*16, inverse-swizzled. 8 lanes per 128B line (coalesced).
  const int srow = tid >> 3;  // 0..63
  const int scolsw = ((tid & 7) * 16) ^ ((srow & 7) << 4);
  const char* Ab = (const char*)A + (size_t)bm * 256 * 2048;
  const char* Bb = (const char*)Bw + (size_t)bn * 128 * 2048;
  const char* Asrc[4];
  const char* Bsrc[2];
#pragma unroll
  for (int j = 0; j < 4; ++j)
    Asrc[j] = Ab + (size_t)(j * 64 + srow) * 2048 + scolsw;
#pragma unroll
  for (int j = 0; j < 2; ++j)
    Bsrc[j] = Bb + (size_t)(j * 64 + srow) * 2048 + scolsw;

  auto stage = [&](int t) {
    char* slot = lds + (t & 1) * 49152;
    const int k0 = t * 128;  // byte offset along K
#pragma unroll
    for (int j = 0; j < 4; ++j) gload16(Asrc[j] + k0, slot + j * 8192 + w * 1024);
#pragma unroll
    for (int j = 0; j < 2; ++j) gload16(Bsrc[j] + k0, slot + 32768 + j * 8192 + w * 1024);
  };

  stage(0);

  for (int t = 0; t < 16; ++t) {
    if (t < 15) {
      stage(t + 1);  // slot (t+1)&1 was released by closing barrier of t-1
      asm volatile("s_waitcnt vmcnt(6)" ::: "memory");  // own stage(t) landed
    } else {
      asm volatile("s_waitcnt vmcnt(0)" ::: "memory");  // tail: drain
    }
    __builtin_amdgcn_s_barrier();  // all waves' stage(t) landed
    asm volatile("" ::: "memory");

    const char* slot = lds + (t & 1) * 49152;
#pragma unroll
    for (int kk = 0; kk < 2; ++kk) {
      h8 b[4];
#pragma unroll
      for (int ni = 0; ni < 4; ++ni) {
        int row = wn * 64 + ni * 16 + c;
        int off = row * 128 + kk * 64 + g * 16;
        b[ni] = *(const h8*)(slot + 32768 + (off ^ ((row & 7) << 4)));
      }
      h8 a[4];
#pragma unroll
      for (int mi = 0; mi < 4; ++mi) {
        int row = wm * 64 + mi * 16 + c;
        int off = row * 128 + kk * 64 + g * 16;
        a[mi] = *(const h8*)(slot + (off ^ ((row & 7) << 4)));
      }
      __builtin_amdgcn_s_setprio(1);
#pragma unroll
      for (int mi = 0; mi < 4; ++mi)
#pragma unroll
        for (int ni = 0; ni < 4; ++ni)
          acc[mi][ni] = __builtin_amdgcn_mfma_f32_16x16x32_f16(a[mi], b[ni], acc[mi][ni], 0, 0, 0);
      __builtin_amdgcn_s_setprio(0);
    }

    __builtin_amdgcn_s_barrier();  // release slot t&1 for overwrite at t+2
    asm volatile("" ::: "memory");
  }

  if (MODE == 0 && bn >= 16) {
    // V segment -> Vt [bh][dk][s]: 4 consecutive s rows -> one h4 store
#pragma unroll
    for (int mi = 0; mi < 4; ++mi)
#pragma unroll
      for (int ni = 0; ni < 4; ++ni) {
        int m0 = bm * 256 + wm * 64 + mi * 16 + g * 4;
        int n = bn * 128 + wn * 64 + ni * 16 + c;
        float bb = bias[n];
        h4 v4;
#pragma unroll
        for (int r = 0; r < 4; ++r) v4[r] = (_Float16)(acc[mi][ni][r] + bb);
        int bI = m0 >> 11, sI = m0 & 2047;
        int dk = n & 63, hh = (n >> 6) & 15;
        *(h4*)(Vt + (((size_t)(bI * 16 + hh) * 64 + dk) * 2048 + sI)) = v4;
      }
  } else {
#pragma unroll
    for (int mi = 0; mi < 4; ++mi)
#pragma unroll
      for (int ni = 0; ni < 4; ++ni)
#pragma unroll
        for (int r = 0; r < 4; ++r) {
          int m = bm * 256 + wm * 64 + mi * 16 + g * 4 + r;
          int n = bn * 128 + wn * 64 + ni * 16 + c;
          float v = acc[mi][ni][r] + bias[n];
          if (MODE == 0) {
            int which = n >> 10, nn = n & 1023;
            int bI = m >> 11, sI = m & 2047, hI = nn >> 6, dkI = nn & 63;
            ((_Float16*)Cout)[(size_t)which * 8388608 +
                              (((size_t)bI * H_ + hI) * S_ + sI) * DK_ + dkI] = (_Float16)v;
          } else {
            ((float*)Cout)[(size_t)m * D_ + n] = v;
          }
        }
  }
}

// ---------------- causal flash attention (r11 verbatim — measured 79us) ----
// 256 blocks x 8 waves; paired supertiles (pi, 7-pi) phase loop -> uniform
// 36 KV64 tiles/block (no dispatch-order assumptions). 32x32 MFMA, in-reg P,
// blk-major K/V LDS (0 conflicts), 3-slot ring, counted vmcnt(2), raw
// barriers, bh-inner L2 mapping.
__global__ __launch_bounds__(512) void attn_fwd(const _Float16* __restrict__ Q,
                                                const _Float16* __restrict__ K,
                                                const _Float16* __restrict__ Vt,
                                                _Float16* __restrict__ vals) {
  __shared__ char lds[3 * 16384];  // 48KB ring

  const int tid = threadIdx.x;
  const int w = tid >> 6;            // wave 0..7
  const int lane = tid & 63;
  const int l31 = lane & 31, hi = lane >> 5;
  const int bid = blockIdx.x;        // 256 = 4 pairs x 64 bh
  const int pi = bid >> 6;           // 0..3
  const int bh = bid & 63;           // bh-inner -> per-XCD L2 residency
  const int bI = bh >> 4, hI = bh & 15;

  const char* Qb = (const char*)(Q + (size_t)bh * S_ * DK_);
  const char* Kb = (const char*)(K + (size_t)bh * S_ * DK_);
  const char* Vtb = (const char*)(Vt + (size_t)bh * DK_ * S_);

  // staging: blk-major transpose via per-lane source (LDS dest linear).
  auto stage = [&](int sloti, int kv0) {
    char* buf = lds + sloti * 16384;
    gload16(Kb + (size_t)kv0 * 128 + (size_t)lane * 128 + w * 16, buf + w * 1024);
    gload16(Vtb + (size_t)lane * 4096 + (size_t)kv0 * 2 + w * 16, buf + 8192 + w * 1024);
  };

  // fragment read offsets: contiguous 16B x 32 lanes (conflict-free)
  int rdo[4];
#pragma unroll
  for (int ks = 0; ks < 4; ++ks) rdo[ks] = (ks * 2 + hi) * 1024 + l31 * 16;

  const _Float16 qsc = (_Float16)(0.125f * 1.44269504f);  // scale * log2(e)

  for (int phase = 0; phase < 2; ++phase) {
    const int sup = (phase == 0) ? pi : 7 - pi;  // 256q supertile index
    const int qw = sup * 8 + w;                  // this wave's 32q tile
    const int nt = 4 * sup + 4;                  // block-uniform tiles

    h8 qf[4];
#pragma unroll
    for (int ks = 0; ks < 4; ++ks) {
      h8 v = *(const h8*)(Qb + (size_t)(qw * 32 + l31) * 128 + ks * 32 + hi * 16);
#pragma unroll
      for (int j = 0; j < 8; ++j) v[j] *= qsc;
      qf[ks] = v;
    }

    f32x16 o[2] = {};                 // dk 0..31, 32..63
    float m_ = -1e30f, l_ = 0.f;

    stage(0, 0);
    stage(1, 64);
    asm volatile("s_waitcnt vmcnt(2)" ::: "memory");  // tile 0 landed
    __builtin_amdgcn_s_barrier();
    asm volatile("" ::: "memory");

    for (int t = 0; t < nt; ++t) {
      const char* ldsb = lds + (t % 3) * 16384;
      if (t + 2 < nt) stage((t + 2) % 3, (t + 2) * 64);

      const int rel = qw - 2 * t;
      if (rel >= 0) {
        const bool have1 = (rel >= 1);

        // S^T = K Q^T : C col = q = l31, row kv = (r&3)+8*(r>>2)+4*hi (+32)
        f32x16 s0 = {}, s1 = {};
#pragma unroll
        for (int ks = 0; ks < 4; ++ks) {
          h8 k0 = *(const h8*)(ldsb + rdo[ks]);
          __builtin_amdgcn_s_setprio(1);
          s0 = __builtin_amdgcn_mfma_f32_32x32x16_f16(k0, qf[ks], s0, 0, 0, 0);
          __builtin_amdgcn_s_setprio(0);
          if (have1) {
            h8 k1 = *(const h8*)(ldsb + rdo[ks] + 512);
            __builtin_amdgcn_s_setprio(1);
            s1 = __builtin_amdgcn_mfma_f32_32x32x16_f16(k1, qf[ks], s1, 0, 0, 0);
            __builtin_amdgcn_s_setprio(0);
          }
        }

        if (rel == 0) {
#pragma unroll
          for (int r = 0; r < 16; ++r) {
            int rowidx = (r & 3) + 8 * (r >> 2) + 4 * hi;
            if (rowidx > l31) s0[r] = -1e30f;
          }
        } else if (rel == 1) {
#pragma unroll
          for (int r = 0; r < 16; ++r) {
            int rowidx = (r & 3) + 8 * (r >> 2) + 4 * hi;
            if (rowidx > l31) s1[r] = -1e30f;
          }
        }

        // per-lane max tree
        float t8[8];
#pragma unroll
        for (int j = 0; j < 8; ++j) t8[j] = fmaxf(s0[2 * j], s0[2 * j + 1]);
        if (have1)
#pragma unroll
          for (int j = 0; j < 8; ++j) t8[j] = fmaxf(t8[j], fmaxf(s1[2 * j], s1[2 * j + 1]));
        float t4a = fmaxf(t8[0], t8[1]), t4b = fmaxf(t8[2], t8[3]);
        float t4c = fmaxf(t8[4], t8[5]), t4d = fmaxf(t8[6], t8[7]);
        float pmax = fmaxf(fmaxf(t4a, t4b), fmaxf(t4c, t4d));

        // defer-max: no cross-lane reduce in common path
        if (!__all(pmax <= m_ + 8.f)) {
          float rm = fmaxf(pmax, __shfl_xor(pmax, 32));
          float mn = fmaxf(m_, rm);
          float al = __builtin_amdgcn_exp2f(m_ - mn);
          m_ = mn;
          l_ *= al;
#pragma unroll
          for (int r = 0; r < 16; ++r) {
            float av = __shfl(al, (r & 3) + 8 * (r >> 2) + 4 * hi);
            o[0][r] *= av;
            o[1][r] *= av;
          }
        }

        // exp2 + pack to u32 kv-pair words, partial sums
        unsigned int u0[8], u1[8];
        float rsa = 0.f, rsb = 0.f;
#pragma unroll
        for (int j = 0; j < 8; ++j) {
          float e0 = __builtin_amdgcn_exp2f(s0[2 * j] - m_);
          float e1 = __builtin_amdgcn_exp2f(s0[2 * j + 1] - m_);
          rsa += e0 + e1;
          u0[j] = __builtin_bit_cast(unsigned int, __builtin_amdgcn_cvt_pkrtz(e0, e1));
        }
        if (have1) {
#pragma unroll
          for (int j = 0; j < 8; ++j) {
            float e0 = __builtin_amdgcn_exp2f(s1[2 * j] - m_);
            float e1 = __builtin_amdgcn_exp2f(s1[2 * j + 1] - m_);
            rsb += e0 + e1;
            u1[j] = __builtin_bit_cast(unsigned int, __builtin_amdgcn_cvt_pkrtz(e0, e1));
          }
        }
        l_ += rsa + rsb;

        // rebuild PV A-operand in registers: half-swap via shfl_xor(.,32)
        h8 pa0[2], pa1[2];
#pragma unroll
        for (int b = 0; b < 2; ++b) {
          unsigned int ua = u0[4 * b], ub = u0[4 * b + 1];
          unsigned int uc = u0[4 * b + 2], ud = u0[4 * b + 3];
          unsigned int va = hi ? ua : uc, vb = hi ? ub : ud;
          unsigned int xa = __shfl_xor(va, 32), xb = __shfl_xor(vb, 32);
          u32x4 q = {hi ? xa : ua, hi ? xb : ub, hi ? uc : xa, hi ? ud : xb};
          pa0[b] = __builtin_bit_cast(h8, q);
        }
        if (have1) {
#pragma unroll
          for (int b = 0; b < 2; ++b) {
            unsigned int ua = u1[4 * b], ub = u1[4 * b + 1];
            unsigned int uc = u1[4 * b + 2], ud = u1[4 * b + 3];
            unsigned int va = hi ? ua : uc, vb = hi ? ub : ud;
            unsigned int xa = __shfl_xor(va, 32), xb = __shfl_xor(vb, 32);
            u32x4 q = {hi ? xa : ua, hi ? xb : ub, hi ? uc : xa, hi ? ud : xb};
            pa1[b] = __builtin_bit_cast(h8, q);
          }
        }

        // O += P V : B col = dk = l31 (+x*32 -> +512B), k = kv 16-slices
#pragma unroll
        for (int x = 0; x < 2; ++x) {
#pragma unroll
          for (int kvs = 0; kvs < 4; ++kvs) {
            int ni = kvs >> 1, b = kvs & 1;
            if (!have1 && ni == 1) continue;
            h8 vf = *(const h8*)(ldsb + 8192 + rdo[kvs] + x * 512);
            h8 pa = ni ? pa1[b] : pa0[b];
            __builtin_amdgcn_s_setprio(1);
            o[x] = __builtin_amdgcn_mfma_f32_32x32x16_f16(pa, vf, o[x], 0, 0, 0);
            __builtin_amdgcn_s_setprio(0);
          }
        }
      }

      if (t + 2 < nt)
        asm volatile("s_waitcnt vmcnt(2)" ::: "memory");
      else
        asm volatile("s_waitcnt vmcnt(0)" ::: "memory");
      __builtin_amdgcn_s_barrier();
      asm volatile("" ::: "memory");
    }

    // epilogue
    float lt = l_ + __shfl_xor(l_, 32);
    float linv = 1.0f / lt;
#pragma unroll
    for (int r = 0; r < 16; ++r) {
      int qidx = (r & 3) + 8 * (r >> 2) + 4 * hi;
      float inv = __shfl(linv, qidx);
      int qrow = qw * 32 + qidx;
      size_t rowoff = ((size_t)bI * S_ + qrow) * D_ + hI * 64 + l31;
      vals[rowoff] = (_Float16)(o[0][r] * inv);
      vals[rowoff + 32] = (_Float16)(o[1][r] * inv);
    }
  }
}

extern "C" void kernel_launch(void* const* d_in, const int* in_sizes, int n_in,
                              void* d_out, int out_size, void* d_ws, size_t ws_size,
                              hipStream_t stream) {
  const float* x  = (const float*)d_in[0];
  // d_in[1] = mask (fixed causal tril) — hardcoded in attn_fwd
  const float* Wq = (const float*)d_in[2];
  const float* bq = (const float*)d_in[3];
  const float* Wk = (const float*)d_in[4];
  const float* bk = (const float*)d_in[5];
  const float* Wv = (const float*)d_in[6];
  const float* bv = (const float*)d_in[7];
  const float* Wo = (const float*)d_in[8];
  const float* bo = (const float*)d_in[9];
  float* out = (float*)d_out;

  char* ws = (char*)d_ws;
  size_t off = 0;
  auto alloc = [&](size_t bytes) {
    char* p = ws + off;
    off += (bytes + 255) & ~(size_t)255;
    return p;
  };
  _Float16* xb   = (_Float16*)alloc((size_t)B_ * S_ * D_ * 2);           // 16MB
  _Float16* wqkv = (_Float16*)alloc((size_t)3 * D_ * D_ * 2);            // 6MB
  _Float16* wob  = (_Float16*)alloc((size_t)D_ * D_ * 2);                // 2MB
  float*    bqkv = (float*)alloc((size_t)3 * D_ * 4);                    // 12KB
  _Float16* qkvw = (_Float16*)alloc((size_t)2 * B_ * H_ * S_ * DK_ * 2); // 32MB (Q,K)
  _Float16* Vtw  = (_Float16*)alloc((size_t)B_ * H_ * S_ * DK_ * 2);     // 16MB
  _Float16* valw = (_Float16*)alloc((size_t)B_ * S_ * D_ * 2);           // 16MB

  conv_all<<<6144, 256, 0, stream>>>(x, Wq, Wk, Wv, Wo, bq, bk, bv, xb, wqkv, wob, bqkv);

  // fused QKV projection; V written transposed straight to Vtw
  gemm_pipe<0><<<dim3(24, 32), 512, 0, stream>>>(xb, wqkv, bqkv, qkvw, Vtw);

  attn_fwd<<<256, 512, 0, stream>>>(qkvw, qkvw + (size_t)8388608, Vtw, valw);

  gemm_pipe<1><<<dim3(8, 32), 512, 0, stream>>>(valw, wob, bo, out, nullptr);
}